// Round 7
// baseline (397.073 us; speedup 1.0000x reference)
//
#include <hip/hip_runtime.h>

typedef unsigned short u16;
typedef __bf16 bf16x8 __attribute__((ext_vector_type(8)));
typedef float f32x4 __attribute__((ext_vector_type(4)));
typedef u16 u16x8 __attribute__((ext_vector_type(8)));
typedef u16 u16x4 __attribute__((ext_vector_type(4)));

typedef __attribute__((address_space(1))) const unsigned char gc_u8;
typedef __attribute__((address_space(3))) unsigned char lds_u8;

__device__ inline void gload16(const void* g, void* l) {
    __builtin_amdgcn_global_load_lds((gc_u8*)g, (lds_u8*)l, 16, 0, 0);
}
__device__ inline u16 f2bf(float f) {
    union { __bf16 h; u16 u; } c; c.h = (__bf16)f; return c.u;
}
__device__ inline float bf2f(u16 u) {
    union { u16 u[2]; float f; } c; c.u[0] = 0; c.u[1] = u; return c.f;
}
// Fully-fenced barrier: nothing (incl. register-only ops / ds ops) crosses.
__device__ inline void hard_barrier() {
    __builtin_amdgcn_sched_barrier(0);
    __builtin_amdgcn_s_barrier();
    __builtin_amdgcn_sched_barrier(0);
}
#define WAIT_LGKM0() asm volatile("s_waitcnt lgkmcnt(0)" ::: "memory")
#define WAIT_VMCNT(n) asm volatile("s_waitcnt vmcnt(" #n ")" ::: "memory")

// ---------------- fp32 -> bf16 convert (weights only) ----------------
__global__ __launch_bounds__(256) void cvt_bf16(const float* __restrict__ src,
                                                u16* __restrict__ dst, int n) {
    int i = (blockIdx.x * 256 + threadIdx.x) * 4;
    if (i < n) {
        float4 f = *reinterpret_cast<const float4*>(src + i);
        u16x4 u = { f2bf(f.x), f2bf(f.y), f2bf(f.z), f2bf(f.w) };
        *reinterpret_cast<u16x4*>(dst + i) = u;
    }
}

// ---------------- NT GEMM: C[M,N] = A[M,K] * B[N,K]^T + bias ----------------
// A_F32=1: A fp32 reg-staged + cvt'd in-kernel. A_F32=0: bf16 via global_load_lds.
// B bf16 via global_load_lds. R6-proven fence discipline throughout.
// OUT_MODE: 0 = bf16 [M][N]; 1 = f32 [M][N]; 2 = bf16 V^T head layout (b,h,dk,s).
template <int A_F32, int OUT_MODE>
__global__ __launch_bounds__(256) void gemm_nt(const void* __restrict__ Av,
                                               const u16* __restrict__ B,
                                               const float* __restrict__ bias,
                                               void* __restrict__ Cv,
                                               int M, int N, int K) {
    __shared__ __align__(16) u16 As[2][128][32];
    __shared__ __align__(16) u16 Bs[2][128][32];
    const int t = threadIdx.x, lane = t & 63, w = t >> 6;
    const int wr = w >> 1, wc = w & 1;
    const int l15 = lane & 15, l16 = lane >> 4;
    const int nwg = gridDim.x, ntiles = N >> 7;
    const int wg = blockIdx.x, chunk = nwg >> 3;
    const int swz = (wg & 7) * chunk + (wg >> 3);
    const int bm = (swz / ntiles) * 128, bn = (swz % ntiles) * 128;
    const int row = t >> 1, cc = (t & 1) * 16;   // f32-A staging coords
    const int srow = w * 16 + (lane >> 2);       // gload staging row
    const int sgr = (lane & 3) * 8;
    const float* Af = (const float*)Av;
    const u16* A16 = (const u16*)Av + (size_t)bm * K;
    const u16* Bb = B + (size_t)bn * K;

    f32x4 acc[4][4];
#pragma unroll
    for (int i = 0; i < 4; i++)
#pragma unroll
        for (int j = 0; j < 4; j++) acc[i][j] = (f32x4){0.f, 0.f, 0.f, 0.f};

    float4 f0, f1, f2, f3;
    auto loadA = [&](int k0) {
        const float* A = Af + (size_t)(bm + row) * K + k0 + cc;
        f0 = *(const float4*)(A);
        f1 = *(const float4*)(A + 4);
        f2 = *(const float4*)(A + 8);
        f3 = *(const float4*)(A + 12);
    };
    auto cvtwrite = [&](int c) {
        u16x8 a0 = (u16x8){f2bf(f0.x), f2bf(f0.y), f2bf(f0.z), f2bf(f0.w),
                           f2bf(f1.x), f2bf(f1.y), f2bf(f1.z), f2bf(f1.w)};
        u16x8 a1 = (u16x8){f2bf(f2.x), f2bf(f2.y), f2bf(f2.z), f2bf(f2.w),
                           f2bf(f3.x), f2bf(f3.y), f2bf(f3.z), f2bf(f3.w)};
        *(u16x8*)&As[c][row][cc] = a0;
        *(u16x8*)&As[c][row][cc + 8] = a1;
    };
    auto stageA16 = [&](int c, int k0) {
        gload16(A16 + (size_t)srow * K + k0 + sgr,        &As[c][w * 16][0]);
        gload16(A16 + (size_t)(64 + srow) * K + k0 + sgr, &As[c][64 + w * 16][0]);
    };
    auto stageB = [&](int c, int k0) {
        gload16(Bb + (size_t)srow * K + k0 + sgr,        &Bs[c][w * 16][0]);
        gload16(Bb + (size_t)(64 + srow) * K + k0 + sgr, &Bs[c][64 + w * 16][0]);
    };

    // prologue: stage tile 0
    if constexpr (A_F32) {
        loadA(0);             // 4 f32 loads (oldest)
        stageB(0, 0);         // 2 gloads (newest)
        WAIT_VMCNT(2);        // f32 landed; B(0) in flight
        cvtwrite(0);
    } else {
        stageA16(0, 0);
        stageB(0, 0);
    }

    const int NS = K >> 5;
    for (int i = 0; i < NS; ++i) {
        const int c = i & 1;
        if constexpr (A_F32) {
            if (i + 1 < NS) loadA((i + 1) * 32);   // pure-VGPR loads, pre-barrier
        }
        WAIT_LGKM0();     // all our LDS reads/writes retired before buffers flip
        hard_barrier();   // barrier1: all waves done reading buf c^1
        if (i + 1 < NS) {
            stageB(c ^ 1, (i + 1) * 32);
            if constexpr (A_F32) {
                // outstanding: B(i)=2 (oldest, lands), f32(i+1)=4 (lands), B(i+1)=2 newest fly
                WAIT_VMCNT(2);
                cvtwrite(c ^ 1);
            } else {
                stageA16(c ^ 1, (i + 1) * 32);
                WAIT_VMCNT(4);
            }
        } else {
            WAIT_VMCNT(0);
        }
        hard_barrier();   // barrier2: buf c fully staged for all waves

        bf16x8 afr[4], bfr[4];
#pragma unroll
        for (int mi = 0; mi < 4; mi++)
            afr[mi] = *(const bf16x8*)&As[c][wr * 64 + mi * 16 + l15][l16 * 8];
#pragma unroll
        for (int ni = 0; ni < 4; ni++)
            bfr[ni] = *(const bf16x8*)&Bs[c][wc * 64 + ni * 16 + l15][l16 * 8];
#pragma unroll
        for (int mi = 0; mi < 4; mi++)
#pragma unroll
            for (int ni = 0; ni < 4; ni++)
                acc[mi][ni] = __builtin_amdgcn_mfma_f32_16x16x32_bf16(
                    afr[mi], bfr[ni], acc[mi][ni], 0, 0, 0);
    }

    // epilogue: C/D layout col = lane&15, row = (lane>>4)*4 + r
#pragma unroll
    for (int ni = 0; ni < 4; ni++) {
        const int col = bn + wc * 64 + ni * 16 + l15;
        const float bv = bias[col];
#pragma unroll
        for (int mi = 0; mi < 4; mi++) {
            const int r0 = bm + wr * 64 + mi * 16 + l16 * 4;
            if constexpr (OUT_MODE == 2) {  // V^T head layout (b,h,dk,s), 4 tokens packed
                const int bb = r0 >> 11, ss = r0 & 2047;
                const int hh = col >> 6, dk = col & 63;
                u16x4 pk;
#pragma unroll
                for (int r = 0; r < 4; r++) pk[r] = f2bf(acc[mi][ni][r] + bv);
                *(u16x4*)&((u16*)Cv)[(((size_t)(bb * 16 + hh) * 64 + dk) << 11) + ss] = pk;
            } else {
#pragma unroll
                for (int r = 0; r < 4; r++) {
                    float v = acc[mi][ni][r] + bv;
                    if constexpr (OUT_MODE == 1)
                        ((float*)Cv)[(size_t)(r0 + r) * N + col] = v;
                    else
                        ((u16*)Cv)[(size_t)(r0 + r) * N + col] = f2bf(v);
                }
            }
        }
    }
}

// ---------------- flash attention: BARRIER-FREE, K/V direct from L2 ----------------
// Block = 128 q-rows of one (b,h); each wave OWNS 32 q-rows (no inter-wave sharing).
// K and V^T fragments read directly from global (L2-resident: 512 KB per head).
// Only LDS use: per-wave P bounce. No __syncthreads / s_barrier anywhere.
__global__ __launch_bounds__(256) void attn_fwd(const u16* __restrict__ Q,
                                                const u16* __restrict__ Kg,
                                                const u16* __restrict__ Vt,
                                                const int* __restrict__ mask,
                                                u16* __restrict__ O) {
    constexpr int S = 2048, D = 1024;
    __shared__ __align__(16) u16 Pl[4][32][68];  // per-wave P, padded stride
    const int t = threadIdx.x, lane = t & 63, w = t >> 6;
    const int l15 = lane & 15, l16 = lane >> 4;
    const int wg = blockIdx.x;                   // 1024 blocks, %8==0 -> bijective
    const int swz = (wg & 7) * 128 + (wg >> 3);
    const int q0 = (swz & 15) * 128, h = (swz >> 4) & 15, b = swz >> 8;
    const int qb = q0 + w * 32;                  // this wave's 32 q-rows

    const u16* Khead = Kg + (size_t)b * S * D + h * 64;
    const u16* Vthead = Vt + (size_t)(b * 16 + h) * 64 * 2048;
    const int* mrow = mask + b * S + l15;

    // Q fragments, pre-scaled by 1/sqrt(64)=0.125
    bf16x8 aq[2][2];
#pragma unroll
    for (int qt = 0; qt < 2; qt++)
#pragma unroll
        for (int ks = 0; ks < 2; ks++) {
            const size_t qi = ((size_t)b * S + qb + qt * 16 + l15) * D +
                              h * 64 + ks * 32 + l16 * 8;
            u16x8 raw = *(const u16x8*)&Q[qi];
            bf16x8 qv;
#pragma unroll
            for (int i = 0; i < 8; i++) qv[i] = (__bf16)(bf2f(raw[i]) * 0.125f);
            aq[qt][ks] = qv;
        }

    f32x4 acc[2][4];
#pragma unroll
    for (int qt = 0; qt < 2; qt++)
#pragma unroll
        for (int dt = 0; dt < 4; dt++) acc[qt][dt] = (f32x4){0.f, 0.f, 0.f, 0.f};
    float lsum[2][4] = {};

    for (int kt = 0; kt < S; kt += 64) {
        // QK^T + softmax, per 16-key group (K frags straight from L2)
#pragma unroll
        for (int k4 = 0; k4 < 4; k4++) {
            const float madd = mrow[kt + k4 * 16] ? 0.f : -1.0e9f;
            const u16* kr = Khead + (size_t)(kt + k4 * 16 + l15) * D + l16 * 8;
            bf16x8 kf0 = *(const bf16x8*)kr;
            bf16x8 kf1 = *(const bf16x8*)(kr + 32);
#pragma unroll
            for (int qt = 0; qt < 2; qt++) {
                f32x4 z = (f32x4){0.f, 0.f, 0.f, 0.f};
                z = __builtin_amdgcn_mfma_f32_16x16x32_bf16(aq[qt][0], kf0, z, 0, 0, 0);
                z = __builtin_amdgcn_mfma_f32_16x16x32_bf16(aq[qt][1], kf1, z, 0, 0, 0);
#pragma unroll
                for (int r = 0; r < 4; r++) {
                    float p = __expf(z[r] + madd);
                    lsum[qt][r] += p;
                    Pl[w][qt * 16 + l16 * 4 + r][k4 * 16 + l15] = f2bf(p);
                }
            }
        }

        // PV: P from wave-local LDS (in-order DS per wave, no barrier), V^T from L2
        bf16x8 pa[2][2];
#pragma unroll
        for (int qt = 0; qt < 2; qt++)
#pragma unroll
            for (int ks = 0; ks < 2; ks++)
                pa[qt][ks] = *(const bf16x8*)&Pl[w][qt * 16 + l15][ks * 32 + l16 * 8];
#pragma unroll
        for (int dt = 0; dt < 4; dt++) {
            const u16* vr = Vthead + (size_t)(dt * 16 + l15) * 2048 + kt + l16 * 8;
            bf16x8 vf0 = *(const bf16x8*)vr;
            bf16x8 vf1 = *(const bf16x8*)(vr + 32);
#pragma unroll
            for (int qt = 0; qt < 2; qt++) {
                acc[qt][dt] = __builtin_amdgcn_mfma_f32_16x16x32_bf16(
                    pa[qt][0], vf0, acc[qt][dt], 0, 0, 0);
                acc[qt][dt] = __builtin_amdgcn_mfma_f32_16x16x32_bf16(
                    pa[qt][1], vf1, acc[qt][dt], 0, 0, 0);
            }
        }
    }

    // epilogue: reduce lsum across the 16-lane column groups, divide, store
#pragma unroll
    for (int qt = 0; qt < 2; qt++)
#pragma unroll
        for (int r = 0; r < 4; r++) {
            float v = lsum[qt][r];
#pragma unroll
            for (int off = 8; off >= 1; off >>= 1) v += __shfl_xor(v, off);
            lsum[qt][r] = 1.f / v;
        }
#pragma unroll
    for (int qt = 0; qt < 2; qt++)
#pragma unroll
        for (int dt = 0; dt < 4; dt++)
#pragma unroll
            for (int r = 0; r < 4; r++) {
                const int tok = qb + qt * 16 + l16 * 4 + r;
                O[((size_t)b * S + tok) * D + h * 64 + dt * 16 + l15] =
                    f2bf(acc[qt][dt][r] * lsum[qt][r]);
            }
}

extern "C" void kernel_launch(void* const* d_in, const int* in_sizes, int n_in,
                              void* d_out, int out_size, void* d_ws, size_t ws_size,
                              hipStream_t stream) {
    const float* query = (const float*)d_in[0];
    const float* key   = (const float*)d_in[1];
    const float* value = (const float*)d_in[2];
    const int*   mask  = (const int*)d_in[3];
    const float* Wq = (const float*)d_in[4];
    const float* bq = (const float*)d_in[5];
    const float* Wk = (const float*)d_in[6];
    const float* bk = (const float*)d_in[7];
    const float* Wv = (const float*)d_in[8];
    const float* bv = (const float*)d_in[9];
    const float* Wo = (const float*)d_in[10];
    const float* bo = (const float*)d_in[11];
    float* out = (float*)d_out;

    constexpr int S = 2048, D = 1024;
    constexpr size_t MSZ = (size_t)4 * S * D;   // 8388608
    constexpr size_t WSZ = (size_t)D * D;       // 1048576
    const size_t need = 4 * WSZ * 2 + 4 * MSZ * 2;  // 72 MB
    if (ws_size < need) return;

    char* p = (char*)d_ws;
    u16* Wqb = (u16*)p; p += WSZ * 2;
    u16* Wkb = (u16*)p; p += WSZ * 2;
    u16* Wvb = (u16*)p; p += WSZ * 2;
    u16* Wob = (u16*)p; p += WSZ * 2;
    u16* Xb  = (u16*)p; p += MSZ * 2;  // attn output
    u16* Qb  = (u16*)p; p += MSZ * 2;
    u16* Kb  = (u16*)p; p += MSZ * 2;
    u16* Vtb = (u16*)p; p += MSZ * 2;  // (b,h,dk,s)

    cvt_bf16<<<1024, 256, 0, stream>>>(Wq, Wqb, (int)WSZ);
    cvt_bf16<<<1024, 256, 0, stream>>>(Wk, Wkb, (int)WSZ);
    cvt_bf16<<<1024, 256, 0, stream>>>(Wv, Wvb, (int)WSZ);
    cvt_bf16<<<1024, 256, 0, stream>>>(Wo, Wob, (int)WSZ);

    gemm_nt<1, 0><<<512, 256, 0, stream>>>(query, Wqb, bq, Qb, 8192, 1024, 1024);
    gemm_nt<1, 0><<<512, 256, 0, stream>>>(key,   Wkb, bk, Kb, 8192, 1024, 1024);
    gemm_nt<1, 2><<<512, 256, 0, stream>>>(value, Wvb, bv, Vtb, 8192, 1024, 1024);

    attn_fwd<<<1024, 256, 0, stream>>>(Qb, Kb, Vtb, mask, Xb);

    gemm_nt<0, 1><<<512, 256, 0, stream>>>(Xb, Wob, bo, out, 8192, 1024, 1024);
}

// Round 8
// 269.282 us; speedup vs baseline: 1.4746x; 1.4746x over previous
//
#include <hip/hip_runtime.h>

typedef unsigned short u16;
typedef __bf16 bf16x8 __attribute__((ext_vector_type(8)));
typedef float f32x4 __attribute__((ext_vector_type(4)));
typedef u16 u16x8 __attribute__((ext_vector_type(8)));
typedef u16 u16x4 __attribute__((ext_vector_type(4)));

typedef __attribute__((address_space(1))) const unsigned char gc_u8;
typedef __attribute__((address_space(3))) unsigned char lds_u8;

__device__ inline void gload16(const void* g, void* l) {
    __builtin_amdgcn_global_load_lds((gc_u8*)g, (lds_u8*)l, 16, 0, 0);
}
__device__ inline u16 f2bf(float f) {
    union { __bf16 h; u16 u; } c; c.h = (__bf16)f; return c.u;
}
__device__ inline float bf2f(u16 u) {
    union { u16 u[2]; float f; } c; c.u[0] = 0; c.u[1] = u; return c.f;
}
// Fully-fenced barrier: nothing (incl. register-only ops / ds ops) crosses.
__device__ inline void hard_barrier() {
    __builtin_amdgcn_sched_barrier(0);
    __builtin_amdgcn_s_barrier();
    __builtin_amdgcn_sched_barrier(0);
}
#define WAIT_LGKM0() asm volatile("s_waitcnt lgkmcnt(0)" ::: "memory")
#define WAIT_VMCNT(n) asm volatile("s_waitcnt vmcnt(" #n ")" ::: "memory")

// ---------------- fp32 -> bf16 convert ----------------
__global__ __launch_bounds__(256) void cvt_bf16(const float* __restrict__ src,
                                                u16* __restrict__ dst, int n) {
    int i = (blockIdx.x * 256 + threadIdx.x) * 4;
    if (i < n) {
        float4 f = *reinterpret_cast<const float4*>(src + i);
        u16x4 u = { f2bf(f.x), f2bf(f.y), f2bf(f.z), f2bf(f.w) };
        *reinterpret_cast<u16x4*>(dst + i) = u;
    }
}

// ---------------- NT GEMM: C[M,N] = A[M,K] * B[N,K]^T + bias ----------------
// R6-proven: A,B bf16 via global_load_lds, 2-phase dbuf, hard fences.
// OUT_MODE: 0 = bf16 [M][N]; 1 = f32 [M][N]; 2 = bf16 V^T head layout (b,h,dk,s).
template <int OUT_MODE>
__global__ __launch_bounds__(256) void gemm_nt(const u16* __restrict__ A,
                                               const u16* __restrict__ B,
                                               const float* __restrict__ bias,
                                               void* __restrict__ Cv,
                                               int M, int N, int K) {
    __shared__ __align__(16) u16 As[2][128][32];
    __shared__ __align__(16) u16 Bs[2][128][32];
    const int t = threadIdx.x, lane = t & 63, w = t >> 6;
    const int wr = w >> 1, wc = w & 1;
    const int l15 = lane & 15, l16 = lane >> 4;
    const int nwg = gridDim.x, ntiles = N >> 7;
    const int wg = blockIdx.x, chunk = nwg >> 3;
    const int swz = (wg & 7) * chunk + (wg >> 3);
    const int bm = (swz / ntiles) * 128, bn = (swz % ntiles) * 128;
    const int srow = w * 16 + (lane >> 2);
    const int sgr = (lane & 3) * 8;
    const u16* Ab = A + (size_t)bm * K;
    const u16* Bb = B + (size_t)bn * K;

    f32x4 acc[4][4];
#pragma unroll
    for (int i = 0; i < 4; i++)
#pragma unroll
        for (int j = 0; j < 4; j++) acc[i][j] = (f32x4){0.f, 0.f, 0.f, 0.f};

    auto stage = [&](int c, int k0) {
        gload16(Ab + (size_t)srow * K + k0 + sgr,        &As[c][w * 16][0]);
        gload16(Ab + (size_t)(64 + srow) * K + k0 + sgr, &As[c][64 + w * 16][0]);
        gload16(Bb + (size_t)srow * K + k0 + sgr,        &Bs[c][w * 16][0]);
        gload16(Bb + (size_t)(64 + srow) * K + k0 + sgr, &Bs[c][64 + w * 16][0]);
    };

    stage(0, 0);
    __syncthreads();  // one-time full drain: buf0 staged

    const int NS = K >> 5;
    for (int ks = 0; ks < NS; ks += 2) {
#pragma unroll
        for (int hf = 0; hf < 2; hf++) {
            const int c = hf;
            const int kn = ks + hf + 1;  // next tile index
            WAIT_LGKM0();     // our LDS reads fully retired before anyone overwrites
            hard_barrier();   // barrier1: all waves done reading buf c^1
            if (kn < NS) {
                stage(c ^ 1, kn * 32);
                WAIT_VMCNT(4);            // cur landed, next in flight
            } else {
                WAIT_VMCNT(0);
            }
            hard_barrier();   // barrier2: buf c visible to all waves

            bf16x8 afr[4], bfr[4];
#pragma unroll
            for (int mi = 0; mi < 4; mi++)
                afr[mi] = *(const bf16x8*)&As[c][wr * 64 + mi * 16 + l15][l16 * 8];
#pragma unroll
            for (int ni = 0; ni < 4; ni++)
                bfr[ni] = *(const bf16x8*)&Bs[c][wc * 64 + ni * 16 + l15][l16 * 8];
#pragma unroll
            for (int mi = 0; mi < 4; mi++)
#pragma unroll
                for (int ni = 0; ni < 4; ni++)
                    acc[mi][ni] = __builtin_amdgcn_mfma_f32_16x16x32_bf16(
                        afr[mi], bfr[ni], acc[mi][ni], 0, 0, 0);
        }
    }

    // epilogue: C/D layout col = lane&15, row = (lane>>4)*4 + r
#pragma unroll
    for (int ni = 0; ni < 4; ni++) {
        const int col = bn + wc * 64 + ni * 16 + l15;
        const float bv = bias[col];
#pragma unroll
        for (int mi = 0; mi < 4; mi++) {
            const int r0 = bm + wr * 64 + mi * 16 + l16 * 4;
            if constexpr (OUT_MODE == 2) {  // V^T head layout, 4 tokens packed
                const int bb = r0 >> 11, ss = r0 & 2047;
                const int hh = col >> 6, dk = col & 63;
                u16x4 pk;
#pragma unroll
                for (int r = 0; r < 4; r++) pk[r] = f2bf(acc[mi][ni][r] + bv);
                *(u16x4*)&((u16*)Cv)[(((size_t)(bb * 16 + hh) * 64 + dk) << 11) + ss] = pk;
            } else {
#pragma unroll
                for (int r = 0; r < 4; r++) {
                    float v = acc[mi][ni][r] + bv;
                    if constexpr (OUT_MODE == 1)
                        ((float*)Cv)[(size_t)(r0 + r) * N + col] = v;
                    else
                        ((u16*)Cv)[(size_t)(r0 + r) * N + col] = f2bf(v);
                }
            }
        }
    }
}

// ---------------- flash attention (no-max softmax, dbuf KV, swizzled LDS) ----------------
// 128 q-rows per block (4 waves x 32 q). KV tiles of 64, double-buffered, fenced.
// K/V LDS XOR-granule swizzle: source granule g^((row>>1)&3), read same XOR.
// 32 q/wave amortizes the shared K/V LDS fragment reads (DS-pipe is the binding
// resource per the R6 cycle model) and halves barrier count per q-row.
__global__ __launch_bounds__(256) void attn_fwd(const u16* __restrict__ Q,
                                                const u16* __restrict__ Kg,
                                                const u16* __restrict__ Vt,
                                                const int* __restrict__ mask,
                                                u16* __restrict__ O) {
    constexpr int S = 2048, D = 1024;
    __shared__ __align__(16) u16 Kl[2][2][64][32];  // [buf][dk-half][key][dk32]
    __shared__ __align__(16) u16 Vl[2][2][64][32];  // [buf][k-half][dk][k32]
    __shared__ __align__(16) u16 Pl[4][32][68];     // per-wave P, padded stride
    __shared__ unsigned Mb[64];                     // 2048-key mask bitmap
    const int t = threadIdx.x, lane = t & 63, w = t >> 6;
    const int l15 = lane & 15, l16 = lane >> 4;
    const int wg = blockIdx.x;                      // 1024 blocks, %8==0 -> bijective
    const int swz = (wg & 7) * 128 + (wg >> 3);
    const int q0 = (swz & 15) * 128, h = (swz >> 4) & 15, b = swz >> 8;
    const int qb = q0 + w * 32;                     // this wave's 32 q-rows
    const int srow = w * 16 + (lane >> 2);
    const int sgr = ((lane & 3) ^ ((lane >> 3) & 3)) * 8;   // pre-swizzled source granule
    const int gsw8 = (l16 ^ ((l15 >> 1) & 3)) * 8;          // swizzled read granule

    const u16* Khead = Kg + (size_t)b * S * D + h * 64;
    const u16* Vthead = Vt + (size_t)(b * 16 + h) * 64 * 2048;
    const int* mrow = mask + b * S;

    auto stage = [&](int c, int kt) {
        gload16(Khead + (size_t)(kt + srow) * D + sgr,        &Kl[c][0][w * 16][0]);
        gload16(Khead + (size_t)(kt + srow) * D + 32 + sgr,   &Kl[c][1][w * 16][0]);
        gload16(Vthead + (size_t)srow * 2048 + kt + sgr,      &Vl[c][0][w * 16][0]);
        gload16(Vthead + (size_t)srow * 2048 + kt + 32 + sgr, &Vl[c][1][w * 16][0]);
    };

    stage(0, 0);
    // pack mask bits (once)
#pragma unroll
    for (int j = 0; j < 8; j++) {
        unsigned long long bal = __ballot(mrow[j * 256 + w * 64 + lane] != 0);
        if (lane == 0) {
            Mb[(j * 4 + w) * 2]     = (unsigned)bal;
            Mb[(j * 4 + w) * 2 + 1] = (unsigned)(bal >> 32);
        }
    }

    // Q fragments, pre-scaled by 1/sqrt(64)=0.125
    bf16x8 aq[2][2];
#pragma unroll
    for (int qt = 0; qt < 2; qt++)
#pragma unroll
        for (int ks = 0; ks < 2; ks++) {
            const size_t qi = ((size_t)b * S + qb + qt * 16 + l15) * D +
                              h * 64 + ks * 32 + l16 * 8;
            u16x8 raw = *(const u16x8*)&Q[qi];
            bf16x8 qv;
#pragma unroll
            for (int i = 0; i < 8; i++) qv[i] = (__bf16)(bf2f(raw[i]) * 0.125f);
            aq[qt][ks] = qv;
        }

    f32x4 acc[2][4];
#pragma unroll
    for (int qt = 0; qt < 2; qt++)
#pragma unroll
        for (int dt = 0; dt < 4; dt++) acc[qt][dt] = (f32x4){0.f, 0.f, 0.f, 0.f};
    float lsum[2][4] = {};

    __syncthreads();  // one-time full drain: buf0 staged + Mb visible

    for (int kt = 0; kt < S; kt += 128) {
#pragma unroll
        for (int hf = 0; hf < 2; hf++) {
            const int c = hf;
            const int cur = kt + hf * 64, nxt = cur + 64;
            WAIT_LGKM0();     // our LDS reads fully retired before anyone overwrites
            hard_barrier();   // barrier1
            if (nxt < S) {
                stage(c ^ 1, nxt);
                WAIT_VMCNT(4);
            } else {
                WAIT_VMCNT(0);
            }
            hard_barrier();   // barrier2

            // QK^T + softmax: K frags shared across both q-groups
#pragma unroll
            for (int k4 = 0; k4 < 4; k4++) {
                bf16x8 kf0 = *(const bf16x8*)&Kl[c][0][k4 * 16 + l15][gsw8];
                bf16x8 kf1 = *(const bf16x8*)&Kl[c][1][k4 * 16 + l15][gsw8];
                const int key = cur + k4 * 16 + l15;
                const float madd = ((Mb[key >> 5] >> (key & 31)) & 1u) ? 0.f : -1.0e9f;
#pragma unroll
                for (int qt = 0; qt < 2; qt++) {
                    f32x4 z = (f32x4){0.f, 0.f, 0.f, 0.f};
                    z = __builtin_amdgcn_mfma_f32_16x16x32_bf16(aq[qt][0], kf0, z, 0, 0, 0);
                    z = __builtin_amdgcn_mfma_f32_16x16x32_bf16(aq[qt][1], kf1, z, 0, 0, 0);
#pragma unroll
                    for (int r = 0; r < 4; r++) {
                        float p = __expf(z[r] + madd);
                        lsum[qt][r] += p;
                        Pl[w][qt * 16 + l16 * 4 + r][k4 * 16 + l15] = f2bf(p);
                    }
                }
            }

            // PV: V frags shared across both q-groups
            bf16x8 pa[2][2];
#pragma unroll
            for (int qt = 0; qt < 2; qt++)
#pragma unroll
                for (int ks = 0; ks < 2; ks++)
                    pa[qt][ks] = *(const bf16x8*)&Pl[w][qt * 16 + l15][ks * 32 + l16 * 8];
#pragma unroll
            for (int dt = 0; dt < 4; dt++) {
                bf16x8 vf0 = *(const bf16x8*)&Vl[c][0][dt * 16 + l15][gsw8];
                bf16x8 vf1 = *(const bf16x8*)&Vl[c][1][dt * 16 + l15][gsw8];
#pragma unroll
                for (int qt = 0; qt < 2; qt++) {
                    acc[qt][dt] = __builtin_amdgcn_mfma_f32_16x16x32_bf16(
                        pa[qt][0], vf0, acc[qt][dt], 0, 0, 0);
                    acc[qt][dt] = __builtin_amdgcn_mfma_f32_16x16x32_bf16(
                        pa[qt][1], vf1, acc[qt][dt], 0, 0, 0);
                }
            }
        }
    }

    // epilogue: reduce lsum across the 16-lane column groups, divide, store
#pragma unroll
    for (int qt = 0; qt < 2; qt++)
#pragma unroll
        for (int r = 0; r < 4; r++) {
            float v = lsum[qt][r];
#pragma unroll
            for (int off = 8; off >= 1; off >>= 1) v += __shfl_xor(v, off);
            lsum[qt][r] = 1.f / v;
        }
#pragma unroll
    for (int qt = 0; qt < 2; qt++)
#pragma unroll
        for (int dt = 0; dt < 4; dt++)
#pragma unroll
            for (int r = 0; r < 4; r++) {
                const int tok = qb + qt * 16 + l16 * 4 + r;
                O[((size_t)b * S + tok) * D + h * 64 + dt * 16 + l15] =
                    f2bf(acc[qt][dt][r] * lsum[qt][r]);
            }
}

extern "C" void kernel_launch(void* const* d_in, const int* in_sizes, int n_in,
                              void* d_out, int out_size, void* d_ws, size_t ws_size,
                              hipStream_t stream) {
    const float* query = (const float*)d_in[0];
    const float* key   = (const float*)d_in[1];
    const float* value = (const float*)d_in[2];
    const int*   mask  = (const int*)d_in[3];
    const float* Wq = (const float*)d_in[4];
    const float* bq = (const float*)d_in[5];
    const float* Wk = (const float*)d_in[6];
    const float* bk = (const float*)d_in[7];
    const float* Wv = (const float*)d_in[8];
    const float* bv = (const float*)d_in[9];
    const float* Wo = (const float*)d_in[10];
    const float* bo = (const float*)d_in[11];
    float* out = (float*)d_out;

    constexpr int S = 2048, D = 1024;
    constexpr size_t MSZ = (size_t)4 * S * D;   // 8388608
    constexpr size_t WSZ = (size_t)D * D;       // 1048576
    const size_t need = 4 * WSZ * 2 + 4 * MSZ * 2;  // 72 MB
    if (ws_size < need) return;

    char* p = (char*)d_ws;
    u16* Wqb = (u16*)p; p += WSZ * 2;
    u16* Wkb = (u16*)p; p += WSZ * 2;
    u16* Wvb = (u16*)p; p += WSZ * 2;
    u16* Wob = (u16*)p; p += WSZ * 2;
    u16* Act = (u16*)p; p += MSZ * 2;  // reused: cvt'd activation, then attn output
    u16* Qb  = (u16*)p; p += MSZ * 2;
    u16* Kb  = (u16*)p; p += MSZ * 2;
    u16* Vtb = (u16*)p; p += MSZ * 2;  // (b,h,dk,s)

    cvt_bf16<<<1024, 256, 0, stream>>>(Wq, Wqb, (int)WSZ);
    cvt_bf16<<<1024, 256, 0, stream>>>(Wk, Wkb, (int)WSZ);
    cvt_bf16<<<1024, 256, 0, stream>>>(Wv, Wvb, (int)WSZ);
    cvt_bf16<<<1024, 256, 0, stream>>>(Wo, Wob, (int)WSZ);

    cvt_bf16<<<8192, 256, 0, stream>>>(query, Act, (int)MSZ);
    gemm_nt<0><<<512, 256, 0, stream>>>(Act, Wqb, bq, Qb, 8192, 1024, 1024);
    cvt_bf16<<<8192, 256, 0, stream>>>(key, Act, (int)MSZ);
    gemm_nt<0><<<512, 256, 0, stream>>>(Act, Wkb, bk, Kb, 8192, 1024, 1024);
    cvt_bf16<<<8192, 256, 0, stream>>>(value, Act, (int)MSZ);
    gemm_nt<2><<<512, 256, 0, stream>>>(Act, Wvb, bv, Vtb, 8192, 1024, 1024);

    attn_fwd<<<1024, 256, 0, stream>>>(Qb, Kb, Vtb, mask, Act);

    gemm_nt<1><<<512, 256, 0, stream>>>(Act, Wob, bo, out, 8192, 1024, 1024);
}

// Round 9
// 252.139 us; speedup vs baseline: 1.5748x; 1.0680x over previous
//
#include <hip/hip_runtime.h>

typedef unsigned short u16;
typedef __bf16 bf16x8 __attribute__((ext_vector_type(8)));
typedef float f32x4 __attribute__((ext_vector_type(4)));
typedef u16 u16x8 __attribute__((ext_vector_type(8)));
typedef u16 u16x4 __attribute__((ext_vector_type(4)));

typedef __attribute__((address_space(1))) const unsigned char gc_u8;
typedef __attribute__((address_space(3))) unsigned char lds_u8;

__device__ inline void gload16(const void* g, void* l) {
    __builtin_amdgcn_global_load_lds((gc_u8*)g, (lds_u8*)l, 16, 0, 0);
}
__device__ inline u16 f2bf(float f) {
    union { __bf16 h; u16 u; } c; c.h = (__bf16)f; return c.u;
}
__device__ inline float bf2f(u16 u) {
    union { u16 u[2]; float f; } c; c.u[0] = 0; c.u[1] = u; return c.f;
}
// Fully-fenced barrier: nothing (incl. register-only ops / ds ops) crosses.
__device__ inline void hard_barrier() {
    __builtin_amdgcn_sched_barrier(0);
    __builtin_amdgcn_s_barrier();
    __builtin_amdgcn_sched_barrier(0);
}
#define WAIT_LGKM0() asm volatile("s_waitcnt lgkmcnt(0)" ::: "memory")
#define WAIT_VMCNT(n) asm volatile("s_waitcnt vmcnt(" #n ")" ::: "memory")

// ---------------- fp32 -> bf16 convert ----------------
__global__ __launch_bounds__(256) void cvt_bf16(const float* __restrict__ src,
                                                u16* __restrict__ dst, int n) {
    int i = (blockIdx.x * 256 + threadIdx.x) * 4;
    if (i < n) {
        float4 f = *reinterpret_cast<const float4*>(src + i);
        u16x4 u = { f2bf(f.x), f2bf(f.y), f2bf(f.z), f2bf(f.w) };
        *reinterpret_cast<u16x4*>(dst + i) = u;
    }
}

// ---------------- NT GEMM: C[M,N] = A[M,K] * B[N,K]^T + bias ----------------
// R6-proven: A,B bf16 via global_load_lds, 2-phase dbuf, hard fences. UNCHANGED.
// OUT_MODE: 0 = bf16 [M][N]; 1 = f32 [M][N]; 2 = bf16 V^T head layout (b,h,dk,s).
template <int OUT_MODE>
__global__ __launch_bounds__(256) void gemm_nt(const u16* __restrict__ A,
                                               const u16* __restrict__ B,
                                               const float* __restrict__ bias,
                                               void* __restrict__ Cv,
                                               int M, int N, int K) {
    __shared__ __align__(16) u16 As[2][128][32];
    __shared__ __align__(16) u16 Bs[2][128][32];
    const int t = threadIdx.x, lane = t & 63, w = t >> 6;
    const int wr = w >> 1, wc = w & 1;
    const int l15 = lane & 15, l16 = lane >> 4;
    const int nwg = gridDim.x, ntiles = N >> 7;
    const int wg = blockIdx.x, chunk = nwg >> 3;
    const int swz = (wg & 7) * chunk + (wg >> 3);
    const int bm = (swz / ntiles) * 128, bn = (swz % ntiles) * 128;
    const int srow = w * 16 + (lane >> 2);
    const int sgr = (lane & 3) * 8;
    const u16* Ab = A + (size_t)bm * K;
    const u16* Bb = B + (size_t)bn * K;

    f32x4 acc[4][4];
#pragma unroll
    for (int i = 0; i < 4; i++)
#pragma unroll
        for (int j = 0; j < 4; j++) acc[i][j] = (f32x4){0.f, 0.f, 0.f, 0.f};

    auto stage = [&](int c, int k0) {
        gload16(Ab + (size_t)srow * K + k0 + sgr,        &As[c][w * 16][0]);
        gload16(Ab + (size_t)(64 + srow) * K + k0 + sgr, &As[c][64 + w * 16][0]);
        gload16(Bb + (size_t)srow * K + k0 + sgr,        &Bs[c][w * 16][0]);
        gload16(Bb + (size_t)(64 + srow) * K + k0 + sgr, &Bs[c][64 + w * 16][0]);
    };

    stage(0, 0);
    __syncthreads();

    const int NS = K >> 5;
    for (int ks = 0; ks < NS; ks += 2) {
#pragma unroll
        for (int hf = 0; hf < 2; hf++) {
            const int c = hf;
            const int kn = ks + hf + 1;
            WAIT_LGKM0();
            hard_barrier();
            if (kn < NS) {
                stage(c ^ 1, kn * 32);
                WAIT_VMCNT(4);
            } else {
                WAIT_VMCNT(0);
            }
            hard_barrier();

            bf16x8 afr[4], bfr[4];
#pragma unroll
            for (int mi = 0; mi < 4; mi++)
                afr[mi] = *(const bf16x8*)&As[c][wr * 64 + mi * 16 + l15][l16 * 8];
#pragma unroll
            for (int ni = 0; ni < 4; ni++)
                bfr[ni] = *(const bf16x8*)&Bs[c][wc * 64 + ni * 16 + l15][l16 * 8];
#pragma unroll
            for (int mi = 0; mi < 4; mi++)
#pragma unroll
                for (int ni = 0; ni < 4; ni++)
                    acc[mi][ni] = __builtin_amdgcn_mfma_f32_16x16x32_bf16(
                        afr[mi], bfr[ni], acc[mi][ni], 0, 0, 0);
        }
    }

#pragma unroll
    for (int ni = 0; ni < 4; ni++) {
        const int col = bn + wc * 64 + ni * 16 + l15;
        const float bv = bias[col];
#pragma unroll
        for (int mi = 0; mi < 4; mi++) {
            const int r0 = bm + wr * 64 + mi * 16 + l16 * 4;
            if constexpr (OUT_MODE == 2) {
                const int bb = r0 >> 11, ss = r0 & 2047;
                const int hh = col >> 6, dk = col & 63;
                u16x4 pk;
#pragma unroll
                for (int r = 0; r < 4; r++) pk[r] = f2bf(acc[mi][ni][r] + bv);
                *(u16x4*)&((u16*)Cv)[(((size_t)(bb * 16 + hh) * 64 + dk) << 11) + ss] = pk;
            } else {
#pragma unroll
                for (int r = 0; r < 4; r++) {
                    float v = acc[mi][ni][r] + bv;
                    if constexpr (OUT_MODE == 1)
                        ((float*)Cv)[(size_t)(r0 + r) * N + col] = v;
                    else
                        ((u16*)Cv)[(size_t)(r0 + r) * N + col] = f2bf(v);
                }
            }
        }
    }
}

// ---------------- flash attention: 64 q/wave, K+V frags hoisted to registers ----------------
// Block = 256 q-rows of one (b,h); 4 waves x 64 q. KV tiles of 64, dbuf, fenced,
// XOR-swizzled LDS (all R8-proven). Per tile: 16 b128 K/V frag reads shared by
// 4 q-subtiles -> LDS clk/q drops ~2.7x vs R8 (LDS-BW-bound per R8 model).
__global__ __launch_bounds__(256, 2) void attn_fwd(const u16* __restrict__ Q,
                                                   const u16* __restrict__ Kg,
                                                   const u16* __restrict__ Vt,
                                                   const int* __restrict__ mask,
                                                   u16* __restrict__ O) {
    constexpr int S = 2048, D = 1024;
    __shared__ __align__(16) u16 Kl[2][2][64][32];  // [buf][dk-half][key][dk32]
    __shared__ __align__(16) u16 Vl[2][2][64][32];  // [buf][k-half][dk][k32]
    __shared__ __align__(16) u16 Pl[4][16][68];     // per-wave P (one qt at a time)
    __shared__ unsigned Mb[64];                     // 2048-key mask bitmap
    const int t = threadIdx.x, lane = t & 63, w = t >> 6;
    const int l15 = lane & 15, l16 = lane >> 4;
    const int wg = blockIdx.x;                      // 512 blocks, %8==0 -> bijective
    const int swz = (wg & 7) * 64 + (wg >> 3);
    const int q0 = (swz & 7) * 256, h = (swz >> 3) & 15, b = swz >> 7;
    const int qb = q0 + w * 64;                     // this wave's 64 q-rows
    const int srow = w * 16 + (lane >> 2);
    const int sgr = ((lane & 3) ^ ((lane >> 3) & 3)) * 8;   // pre-swizzled source granule
    const int gsw8 = (l16 ^ ((l15 >> 1) & 3)) * 8;          // swizzled read granule

    const u16* Khead = Kg + (size_t)b * S * D + h * 64;
    const u16* Vthead = Vt + (size_t)(b * 16 + h) * 64 * 2048;
    const int* mrow = mask + b * S;

    auto stage = [&](int c, int kt) {
        gload16(Khead + (size_t)(kt + srow) * D + sgr,        &Kl[c][0][w * 16][0]);
        gload16(Khead + (size_t)(kt + srow) * D + 32 + sgr,   &Kl[c][1][w * 16][0]);
        gload16(Vthead + (size_t)srow * 2048 + kt + sgr,      &Vl[c][0][w * 16][0]);
        gload16(Vthead + (size_t)srow * 2048 + kt + 32 + sgr, &Vl[c][1][w * 16][0]);
    };

    stage(0, 0);
    // pack mask bits (once)
#pragma unroll
    for (int j = 0; j < 8; j++) {
        unsigned long long bal = __ballot(mrow[j * 256 + w * 64 + lane] != 0);
        if (lane == 0) {
            Mb[(j * 4 + w) * 2]     = (unsigned)bal;
            Mb[(j * 4 + w) * 2 + 1] = (unsigned)(bal >> 32);
        }
    }

    // Q fragments (4 q-subtiles), pre-scaled by 1/sqrt(64)=0.125 (exact in bf16)
    bf16x8 aq[4][2];
#pragma unroll
    for (int qt = 0; qt < 4; qt++)
#pragma unroll
        for (int ks = 0; ks < 2; ks++) {
            const size_t qi = ((size_t)b * S + qb + qt * 16 + l15) * D +
                              h * 64 + ks * 32 + l16 * 8;
            u16x8 raw = *(const u16x8*)&Q[qi];
            bf16x8 qv;
#pragma unroll
            for (int i = 0; i < 8; i++) qv[i] = (__bf16)(bf2f(raw[i]) * 0.125f);
            aq[qt][ks] = qv;
        }

    f32x4 acc[4][4];
#pragma unroll
    for (int qt = 0; qt < 4; qt++)
#pragma unroll
        for (int dt = 0; dt < 4; dt++) acc[qt][dt] = (f32x4){0.f, 0.f, 0.f, 0.f};
    float lsum[4][4] = {};

    __syncthreads();  // one-time full drain: buf0 staged + Mb visible

    for (int kt = 0; kt < S; kt += 128) {
#pragma unroll
        for (int hf = 0; hf < 2; hf++) {
            const int c = hf;
            const int cur = kt + hf * 64, nxt = cur + 64;
            WAIT_LGKM0();     // our LDS reads fully retired before anyone overwrites
            hard_barrier();   // barrier1
            if (nxt < S) {
                stage(c ^ 1, nxt);
                WAIT_VMCNT(4);
            } else {
                WAIT_VMCNT(0);
            }
            hard_barrier();   // barrier2

            // hoist ALL K and V fragments for this tile into registers (16 b128)
            bf16x8 kf0[4], kf1[4], vf0[4], vf1[4];
#pragma unroll
            for (int k4 = 0; k4 < 4; k4++) {
                kf0[k4] = *(const bf16x8*)&Kl[c][0][k4 * 16 + l15][gsw8];
                kf1[k4] = *(const bf16x8*)&Kl[c][1][k4 * 16 + l15][gsw8];
            }
#pragma unroll
            for (int dt = 0; dt < 4; dt++) {
                vf0[dt] = *(const bf16x8*)&Vl[c][0][dt * 16 + l15][gsw8];
                vf1[dt] = *(const bf16x8*)&Vl[c][1][dt * 16 + l15][gsw8];
            }
            float madd[4];
#pragma unroll
            for (int k4 = 0; k4 < 4; k4++) {
                const int key = cur + k4 * 16 + l15;
                madd[k4] = ((Mb[key >> 5] >> (key & 31)) & 1u) ? 0.f : -1.0e9f;
            }

            // 4 q-subtiles sequentially; Pl reused (in-order per-wave DS = safe)
#pragma unroll
            for (int qt = 0; qt < 4; qt++) {
#pragma unroll
                for (int k4 = 0; k4 < 4; k4++) {
                    f32x4 z = (f32x4){0.f, 0.f, 0.f, 0.f};
                    z = __builtin_amdgcn_mfma_f32_16x16x32_bf16(aq[qt][0], kf0[k4], z, 0, 0, 0);
                    z = __builtin_amdgcn_mfma_f32_16x16x32_bf16(aq[qt][1], kf1[k4], z, 0, 0, 0);
#pragma unroll
                    for (int r = 0; r < 4; r++) {
                        float p = __expf(z[r] + madd[k4]);
                        lsum[qt][r] += p;
                        Pl[w][l16 * 4 + r][k4 * 16 + l15] = f2bf(p);
                    }
                }
                bf16x8 pa0 = *(const bf16x8*)&Pl[w][l15][l16 * 8];
                bf16x8 pa1 = *(const bf16x8*)&Pl[w][l15][32 + l16 * 8];
#pragma unroll
                for (int dt = 0; dt < 4; dt++) {
                    acc[qt][dt] = __builtin_amdgcn_mfma_f32_16x16x32_bf16(
                        pa0, vf0[dt], acc[qt][dt], 0, 0, 0);
                    acc[qt][dt] = __builtin_amdgcn_mfma_f32_16x16x32_bf16(
                        pa1, vf1[dt], acc[qt][dt], 0, 0, 0);
                }
            }
        }
    }

    // epilogue: reduce lsum across l15 lanes, divide, store
#pragma unroll
    for (int qt = 0; qt < 4; qt++)
#pragma unroll
        for (int r = 0; r < 4; r++) {
            float v = lsum[qt][r];
#pragma unroll
            for (int off = 8; off >= 1; off >>= 1) v += __shfl_xor(v, off);
            lsum[qt][r] = 1.f / v;
        }
#pragma unroll
    for (int qt = 0; qt < 4; qt++)
#pragma unroll
        for (int dt = 0; dt < 4; dt++)
#pragma unroll
            for (int r = 0; r < 4; r++) {
                const int tok = qb + qt * 16 + l16 * 4 + r;
                O[((size_t)b * S + tok) * D + h * 64 + dt * 16 + l15] =
                    f2bf(acc[qt][dt][r] * lsum[qt][r]);
            }
}

extern "C" void kernel_launch(void* const* d_in, const int* in_sizes, int n_in,
                              void* d_out, int out_size, void* d_ws, size_t ws_size,
                              hipStream_t stream) {
    const float* query = (const float*)d_in[0];
    const float* key   = (const float*)d_in[1];
    const float* value = (const float*)d_in[2];
    const int*   mask  = (const int*)d_in[3];
    const float* Wq = (const float*)d_in[4];
    const float* bq = (const float*)d_in[5];
    const float* Wk = (const float*)d_in[6];
    const float* bk = (const float*)d_in[7];
    const float* Wv = (const float*)d_in[8];
    const float* bv = (const float*)d_in[9];
    const float* Wo = (const float*)d_in[10];
    const float* bo = (const float*)d_in[11];
    float* out = (float*)d_out;

    constexpr int S = 2048, D = 1024;
    constexpr size_t MSZ = (size_t)4 * S * D;   // 8388608
    constexpr size_t WSZ = (size_t)D * D;       // 1048576
    const size_t need = 4 * WSZ * 2 + 4 * MSZ * 2;  // 72 MB
    if (ws_size < need) return;

    char* p = (char*)d_ws;
    u16* Wqb = (u16*)p; p += WSZ * 2;
    u16* Wkb = (u16*)p; p += WSZ * 2;
    u16* Wvb = (u16*)p; p += WSZ * 2;
    u16* Wob = (u16*)p; p += WSZ * 2;
    u16* Act = (u16*)p; p += MSZ * 2;  // reused: cvt'd activation, then attn output
    u16* Qb  = (u16*)p; p += MSZ * 2;
    u16* Kb  = (u16*)p; p += MSZ * 2;
    u16* Vtb = (u16*)p; p += MSZ * 2;  // (b,h,dk,s)

    cvt_bf16<<<1024, 256, 0, stream>>>(Wq, Wqb, (int)WSZ);
    cvt_bf16<<<1024, 256, 0, stream>>>(Wk, Wkb, (int)WSZ);
    cvt_bf16<<<1024, 256, 0, stream>>>(Wv, Wvb, (int)WSZ);
    cvt_bf16<<<1024, 256, 0, stream>>>(Wo, Wob, (int)WSZ);

    cvt_bf16<<<8192, 256, 0, stream>>>(query, Act, (int)MSZ);
    gemm_nt<0><<<512, 256, 0, stream>>>(Act, Wqb, bq, Qb, 8192, 1024, 1024);
    cvt_bf16<<<8192, 256, 0, stream>>>(key, Act, (int)MSZ);
    gemm_nt<0><<<512, 256, 0, stream>>>(Act, Wkb, bk, Kb, 8192, 1024, 1024);
    cvt_bf16<<<8192, 256, 0, stream>>>(value, Act, (int)MSZ);
    gemm_nt<2><<<512, 256, 0, stream>>>(Act, Wvb, bv, Vtb, 8192, 1024, 1024);

    attn_fwd<<<512, 256, 0, stream>>>(Qb, Kb, Vtb, mask, Act);

    gemm_nt<1><<<512, 256, 0, stream>>>(Act, Wob, bo, out, 8192, 1024, 1024);
}

// Round 10
// 233.350 us; speedup vs baseline: 1.7016x; 1.0805x over previous
//
#include <hip/hip_runtime.h>

typedef unsigned short u16;
typedef __bf16 bf16x8 __attribute__((ext_vector_type(8)));
typedef float f32x4 __attribute__((ext_vector_type(4)));
typedef u16 u16x8 __attribute__((ext_vector_type(8)));
typedef u16 u16x4 __attribute__((ext_vector_type(4)));

typedef __attribute__((address_space(1))) const unsigned char gc_u8;
typedef __attribute__((address_space(3))) unsigned char lds_u8;

__device__ inline void gload16(const void* g, void* l) {
    __builtin_amdgcn_global_load_lds((gc_u8*)g, (lds_u8*)l, 16, 0, 0);
}
__device__ inline u16 f2bf(float f) {
    union { __bf16 h; u16 u; } c; c.h = (__bf16)f; return c.u;
}
__device__ inline float bf2f(u16 u) {
    union { u16 u[2]; float f; } c; c.u[0] = 0; c.u[1] = u; return c.f;
}
// Fully-fenced barrier: nothing (incl. register-only ops / ds ops) crosses.
__device__ inline void hard_barrier() {
    __builtin_amdgcn_sched_barrier(0);
    __builtin_amdgcn_s_barrier();
    __builtin_amdgcn_sched_barrier(0);
}
#define WAIT_LGKM0() asm volatile("s_waitcnt lgkmcnt(0)" ::: "memory")
#define WAIT_VMCNT(n) asm volatile("s_waitcnt vmcnt(" #n ")" ::: "memory")

// ---------------- fp32 -> bf16 convert ----------------
__global__ __launch_bounds__(256) void cvt_bf16(const float* __restrict__ src,
                                                u16* __restrict__ dst, int n) {
    int i = (blockIdx.x * 256 + threadIdx.x) * 4;
    if (i < n) {
        float4 f = *reinterpret_cast<const float4*>(src + i);
        u16x4 u = { f2bf(f.x), f2bf(f.y), f2bf(f.z), f2bf(f.w) };
        *reinterpret_cast<u16x4*>(dst + i) = u;
    }
}

// ---------------- NT GEMM: C[M,N] = A[M,K] * B[N,K]^T + bias ----------------
// R6-proven: A,B bf16 via global_load_lds, 2-phase dbuf, hard fences. UNCHANGED.
// OUT_MODE: 0 = bf16 [M][N]; 1 = f32 [M][N]; 2 = bf16 V^T head layout (b,h,dk,s).
template <int OUT_MODE>
__global__ __launch_bounds__(256) void gemm_nt(const u16* __restrict__ A,
                                               const u16* __restrict__ B,
                                               const float* __restrict__ bias,
                                               void* __restrict__ Cv,
                                               int M, int N, int K) {
    __shared__ __align__(16) u16 As[2][128][32];
    __shared__ __align__(16) u16 Bs[2][128][32];
    const int t = threadIdx.x, lane = t & 63, w = t >> 6;
    const int wr = w >> 1, wc = w & 1;
    const int l15 = lane & 15, l16 = lane >> 4;
    const int nwg = gridDim.x, ntiles = N >> 7;
    const int wg = blockIdx.x, chunk = nwg >> 3;
    const int swz = (wg & 7) * chunk + (wg >> 3);
    const int bm = (swz / ntiles) * 128, bn = (swz % ntiles) * 128;
    const int srow = w * 16 + (lane >> 2);
    const int sgr = (lane & 3) * 8;
    const u16* Ab = A + (size_t)bm * K;
    const u16* Bb = B + (size_t)bn * K;

    f32x4 acc[4][4];
#pragma unroll
    for (int i = 0; i < 4; i++)
#pragma unroll
        for (int j = 0; j < 4; j++) acc[i][j] = (f32x4){0.f, 0.f, 0.f, 0.f};

    auto stage = [&](int c, int k0) {
        gload16(Ab + (size_t)srow * K + k0 + sgr,        &As[c][w * 16][0]);
        gload16(Ab + (size_t)(64 + srow) * K + k0 + sgr, &As[c][64 + w * 16][0]);
        gload16(Bb + (size_t)srow * K + k0 + sgr,        &Bs[c][w * 16][0]);
        gload16(Bb + (size_t)(64 + srow) * K + k0 + sgr, &Bs[c][64 + w * 16][0]);
    };

    stage(0, 0);
    __syncthreads();

    const int NS = K >> 5;
    for (int ks = 0; ks < NS; ks += 2) {
#pragma unroll
        for (int hf = 0; hf < 2; hf++) {
            const int c = hf;
            const int kn = ks + hf + 1;
            WAIT_LGKM0();
            hard_barrier();
            if (kn < NS) {
                stage(c ^ 1, kn * 32);
                WAIT_VMCNT(4);
            } else {
                WAIT_VMCNT(0);
            }
            hard_barrier();

            bf16x8 afr[4], bfr[4];
#pragma unroll
            for (int mi = 0; mi < 4; mi++)
                afr[mi] = *(const bf16x8*)&As[c][wr * 64 + mi * 16 + l15][l16 * 8];
#pragma unroll
            for (int ni = 0; ni < 4; ni++)
                bfr[ni] = *(const bf16x8*)&Bs[c][wc * 64 + ni * 16 + l15][l16 * 8];
#pragma unroll
            for (int mi = 0; mi < 4; mi++)
#pragma unroll
                for (int ni = 0; ni < 4; ni++)
                    acc[mi][ni] = __builtin_amdgcn_mfma_f32_16x16x32_bf16(
                        afr[mi], bfr[ni], acc[mi][ni], 0, 0, 0);
        }
    }

#pragma unroll
    for (int ni = 0; ni < 4; ni++) {
        const int col = bn + wc * 64 + ni * 16 + l15;
        const float bv = bias[col];
#pragma unroll
        for (int mi = 0; mi < 4; mi++) {
            const int r0 = bm + wr * 64 + mi * 16 + l16 * 4;
            if constexpr (OUT_MODE == 2) {
                const int bb = r0 >> 11, ss = r0 & 2047;
                const int hh = col >> 6, dk = col & 63;
                u16x4 pk;
#pragma unroll
                for (int r = 0; r < 4; r++) pk[r] = f2bf(acc[mi][ni][r] + bv);
                *(u16x4*)&((u16*)Cv)[(((size_t)(bb * 16 + hh) * 64 + dk) << 11) + ss] = pk;
            } else {
#pragma unroll
                for (int r = 0; r < 4; r++) {
                    float v = acc[mi][ni][r] + bv;
                    if constexpr (OUT_MODE == 1)
                        ((float*)Cv)[(size_t)(r0 + r) * N + col] = v;
                    else
                        ((u16*)Cv)[(size_t)(r0 + r) * N + col] = f2bf(v);
                }
            }
        }
    }
}

// ---------------- flash attention: swapped-QK softmax, packed P, MFMA row-sums ----------------
// Block = 256 q of one (b,h); 4 waves x 64 q; KV tiles 64, dbuf + fences (R8/R9-proven).
// mfma(K,Q) puts P[key][q] with 4 CONSECUTIVE keys per lane -> packed b64 P store.
// lsum = P x ones-fragment MFMA (per-q row sums in-register, no shuffles).
// exp2 with Q prescaled by 0.125*log2(e).
__global__ __launch_bounds__(256, 2) void attn_fwd(const u16* __restrict__ Q,
                                                   const u16* __restrict__ Kg,
                                                   const u16* __restrict__ Vt,
                                                   const int* __restrict__ mask,
                                                   u16* __restrict__ O) {
    constexpr int S = 2048, D = 1024;
    __shared__ __align__(16) u16 Kl[2][2][64][32];  // [buf][dk-half][key][dk32]
    __shared__ __align__(16) u16 Vl[2][2][64][32];  // [buf][k-half][dk][k32]
    __shared__ __align__(16) u16 Pl[4][16][68];     // per-wave P: rows=q(16), cols=64 keys
    __shared__ unsigned Mb[64];                     // 2048-key mask bitmap
    const int t = threadIdx.x, lane = t & 63, w = t >> 6;
    const int l15 = lane & 15, l16 = lane >> 4;
    const int wg = blockIdx.x;                      // 512 blocks, %8==0 -> bijective
    const int swz = (wg & 7) * 64 + (wg >> 3);
    const int q0 = (swz & 7) * 256, h = (swz >> 3) & 15, b = swz >> 7;
    const int qb = q0 + w * 64;
    const int srow = w * 16 + (lane >> 2);
    const int sgr = ((lane & 3) ^ ((lane >> 3) & 3)) * 8;   // pre-swizzled source granule
    const int gsw8 = (l16 ^ ((l15 >> 1) & 3)) * 8;          // swizzled read granule

    const u16* Khead = Kg + (size_t)b * S * D + h * 64;
    const u16* Vthead = Vt + (size_t)(b * 16 + h) * 64 * 2048;
    const int* mrow = mask + b * S;

    auto stage = [&](int c, int kt) {
        gload16(Khead + (size_t)(kt + srow) * D + sgr,        &Kl[c][0][w * 16][0]);
        gload16(Khead + (size_t)(kt + srow) * D + 32 + sgr,   &Kl[c][1][w * 16][0]);
        gload16(Vthead + (size_t)srow * 2048 + kt + sgr,      &Vl[c][0][w * 16][0]);
        gload16(Vthead + (size_t)srow * 2048 + kt + 32 + sgr, &Vl[c][1][w * 16][0]);
    };

    stage(0, 0);
    // pack mask bits (once)
#pragma unroll
    for (int j = 0; j < 8; j++) {
        unsigned long long bal = __ballot(mrow[j * 256 + w * 64 + lane] != 0);
        if (lane == 0) {
            Mb[(j * 4 + w) * 2]     = (unsigned)bal;
            Mb[(j * 4 + w) * 2 + 1] = (unsigned)(bal >> 32);
        }
    }

    // Q fragments (4 q-subtiles), pre-scaled by 0.125 * log2(e)
    constexpr float QSCALE = 0.125f * 1.44269504f;
    bf16x8 aq[4][2];
#pragma unroll
    for (int qt = 0; qt < 4; qt++)
#pragma unroll
        for (int ks = 0; ks < 2; ks++) {
            const size_t qi = ((size_t)b * S + qb + qt * 16 + l15) * D +
                              h * 64 + ks * 32 + l16 * 8;
            u16x8 raw = *(const u16x8*)&Q[qi];
            bf16x8 qv;
#pragma unroll
            for (int i = 0; i < 8; i++) qv[i] = (__bf16)(bf2f(raw[i]) * QSCALE);
            aq[qt][ks] = qv;
        }

    bf16x8 ones;
#pragma unroll
    for (int i = 0; i < 8; i++) ones[i] = (__bf16)1.0f;

    f32x4 acc[4][4];
    f32x4 accl[4];
#pragma unroll
    for (int qt = 0; qt < 4; qt++) {
        accl[qt] = (f32x4){0.f, 0.f, 0.f, 0.f};
#pragma unroll
        for (int dt = 0; dt < 4; dt++) acc[qt][dt] = (f32x4){0.f, 0.f, 0.f, 0.f};
    }

    __syncthreads();  // one-time full drain: buf0 staged + Mb visible

    for (int kt = 0; kt < S; kt += 128) {
#pragma unroll
        for (int hf = 0; hf < 2; hf++) {
            const int c = hf;
            const int cur = kt + hf * 64, nxt = cur + 64;
            WAIT_LGKM0();     // our LDS reads fully retired before anyone overwrites
            hard_barrier();   // barrier1
            if (nxt < S) {
                stage(c ^ 1, nxt);
                WAIT_VMCNT(4);
            } else {
                WAIT_VMCNT(0);
            }
            hard_barrier();   // barrier2

            // hoist ALL K and V fragments for this tile into registers (16 b128)
            bf16x8 kf0[4], kf1[4], vf0[4], vf1[4];
#pragma unroll
            for (int k4 = 0; k4 < 4; k4++) {
                kf0[k4] = *(const bf16x8*)&Kl[c][0][k4 * 16 + l15][gsw8];
                kf1[k4] = *(const bf16x8*)&Kl[c][1][k4 * 16 + l15][gsw8];
            }
#pragma unroll
            for (int dt = 0; dt < 4; dt++) {
                vf0[dt] = *(const bf16x8*)&Vl[c][0][dt * 16 + l15][gsw8];
                vf1[dt] = *(const bf16x8*)&Vl[c][1][dt * 16 + l15][gsw8];
            }

            // per-tile mask adds: key = cur + k4*16 + l16*4 + r (r-indexed!)
            const unsigned w0 = Mb[cur >> 5], w1 = Mb[(cur >> 5) + 1];
            float madd[4][4];
#pragma unroll
            for (int k4 = 0; k4 < 4; k4++) {
                const unsigned wsel = (k4 < 2) ? w0 : w1;
                const unsigned bits = (wsel >> ((k4 & 1) * 16 + l16 * 4)) & 0xFu;
#pragma unroll
                for (int r = 0; r < 4; r++)
                    madd[k4][r] = ((bits >> r) & 1u) ? 0.f : -1.0e9f;
            }

            // 4 q-subtiles; Pl reused per qt (in-order per-wave DS = safe)
#pragma unroll
            for (int qt = 0; qt < 4; qt++) {
#pragma unroll
                for (int k4 = 0; k4 < 4; k4++) {
                    f32x4 z = (f32x4){0.f, 0.f, 0.f, 0.f};
                    // swapped operands: D[key][q], lane: q=l15, keys=l16*4+r
                    z = __builtin_amdgcn_mfma_f32_16x16x32_bf16(kf0[k4], aq[qt][0], z, 0, 0, 0);
                    z = __builtin_amdgcn_mfma_f32_16x16x32_bf16(kf1[k4], aq[qt][1], z, 0, 0, 0);
                    u16x4 pk;
#pragma unroll
                    for (int r = 0; r < 4; r++)
                        pk[r] = f2bf(__builtin_amdgcn_exp2f(z[r] + madd[k4][r]));
                    *(u16x4*)&Pl[w][l15][k4 * 16 + l16 * 4] = pk;  // packed b64
                }
                bf16x8 pa0 = *(const bf16x8*)&Pl[w][l15][l16 * 8];
                bf16x8 pa1 = *(const bf16x8*)&Pl[w][l15][32 + l16 * 8];
                accl[qt] = __builtin_amdgcn_mfma_f32_16x16x32_bf16(pa0, ones, accl[qt], 0, 0, 0);
                accl[qt] = __builtin_amdgcn_mfma_f32_16x16x32_bf16(pa1, ones, accl[qt], 0, 0, 0);
#pragma unroll
                for (int dt = 0; dt < 4; dt++) {
                    acc[qt][dt] = __builtin_amdgcn_mfma_f32_16x16x32_bf16(
                        pa0, vf0[dt], acc[qt][dt], 0, 0, 0);
                    acc[qt][dt] = __builtin_amdgcn_mfma_f32_16x16x32_bf16(
                        pa1, vf1[dt], acc[qt][dt], 0, 0, 0);
                }
            }
        }
    }

    // epilogue: accl[qt][r] is the row sum for q = qt*16 + l16*4 + r (uniform over l15)
#pragma unroll
    for (int qt = 0; qt < 4; qt++) {
        f32x4 inv;
#pragma unroll
        for (int r = 0; r < 4; r++) inv[r] = 1.f / accl[qt][r];
#pragma unroll
        for (int dt = 0; dt < 4; dt++)
#pragma unroll
            for (int r = 0; r < 4; r++) {
                const int tok = qb + qt * 16 + l16 * 4 + r;
                O[((size_t)b * S + tok) * D + h * 64 + dt * 16 + l15] =
                    f2bf(acc[qt][dt][r] * inv[r]);
            }
    }
}

extern "C" void kernel_launch(void* const* d_in, const int* in_sizes, int n_in,
                              void* d_out, int out_size, void* d_ws, size_t ws_size,
                              hipStream_t stream) {
    const float* query = (const float*)d_in[0];
    const float* key   = (const float*)d_in[1];
    const float* value = (const float*)d_in[2];
    const int*   mask  = (const int*)d_in[3];
    const float* Wq = (const float*)d_in[4];
    const float* bq = (const float*)d_in[5];
    const float* Wk = (const float*)d_in[6];
    const float* bk = (const float*)d_in[7];
    const float* Wv = (const float*)d_in[8];
    const float* bv = (const float*)d_in[9];
    const float* Wo = (const float*)d_in[10];
    const float* bo = (const float*)d_in[11];
    float* out = (float*)d_out;

    constexpr int S = 2048, D = 1024;
    constexpr size_t MSZ = (size_t)4 * S * D;   // 8388608
    constexpr size_t WSZ = (size_t)D * D;       // 1048576
    const size_t need = 4 * WSZ * 2 + 4 * MSZ * 2;  // 72 MB
    if (ws_size < need) return;

    char* p = (char*)d_ws;
    u16* Wqb = (u16*)p; p += WSZ * 2;
    u16* Wkb = (u16*)p; p += WSZ * 2;
    u16* Wvb = (u16*)p; p += WSZ * 2;
    u16* Wob = (u16*)p; p += WSZ * 2;
    u16* Act = (u16*)p; p += MSZ * 2;  // reused: cvt'd activation, then attn output
    u16* Qb  = (u16*)p; p += MSZ * 2;
    u16* Kb  = (u16*)p; p += MSZ * 2;
    u16* Vtb = (u16*)p; p += MSZ * 2;  // (b,h,dk,s)

    cvt_bf16<<<1024, 256, 0, stream>>>(Wq, Wqb, (int)WSZ);
    cvt_bf16<<<1024, 256, 0, stream>>>(Wk, Wkb, (int)WSZ);
    cvt_bf16<<<1024, 256, 0, stream>>>(Wv, Wvb, (int)WSZ);
    cvt_bf16<<<1024, 256, 0, stream>>>(Wo, Wob, (int)WSZ);

    cvt_bf16<<<8192, 256, 0, stream>>>(query, Act, (int)MSZ);
    gemm_nt<0><<<512, 256, 0, stream>>>(Act, Wqb, bq, Qb, 8192, 1024, 1024);
    cvt_bf16<<<8192, 256, 0, stream>>>(key, Act, (int)MSZ);
    gemm_nt<0><<<512, 256, 0, stream>>>(Act, Wkb, bk, Kb, 8192, 1024, 1024);
    cvt_bf16<<<8192, 256, 0, stream>>>(value, Act, (int)MSZ);
    gemm_nt<2><<<512, 256, 0, stream>>>(Act, Wvb, bv, Vtb, 8192, 1024, 1024);

    attn_fwd<<<512, 256, 0, stream>>>(Qb, Kb, Vtb, mask, Act);

    gemm_nt<1><<<512, 256, 0, stream>>>(Act, Wob, bo, out, 8192, 1024, 1024);
}

// Round 11
// 206.539 us; speedup vs baseline: 1.9225x; 1.1298x over previous
//
#include <hip/hip_runtime.h>

typedef unsigned short u16;
typedef __bf16 bf16x8 __attribute__((ext_vector_type(8)));
typedef float f32x4 __attribute__((ext_vector_type(4)));
typedef u16 u16x8 __attribute__((ext_vector_type(8)));
typedef u16 u16x4 __attribute__((ext_vector_type(4)));

typedef __attribute__((address_space(1))) const unsigned char gc_u8;
typedef __attribute__((address_space(3))) unsigned char lds_u8;

__device__ inline void gload16(const void* g, void* l) {
    __builtin_amdgcn_global_load_lds((gc_u8*)g, (lds_u8*)l, 16, 0, 0);
}
__device__ inline u16 f2bf(float f) {
    union { __bf16 h; u16 u; } c; c.h = (__bf16)f; return c.u;
}
__device__ inline float bf2f(u16 u) {
    union { u16 u[2]; float f; } c; c.u[0] = 0; c.u[1] = u; return c.f;
}
// Fully-fenced barrier: nothing (incl. register-only ops / ds ops) crosses.
__device__ inline void hard_barrier() {
    __builtin_amdgcn_sched_barrier(0);
    __builtin_amdgcn_s_barrier();
    __builtin_amdgcn_sched_barrier(0);
}
#define WAIT_LGKM0() asm volatile("s_waitcnt lgkmcnt(0)" ::: "memory")
#define WAIT_VMCNT(n) asm volatile("s_waitcnt vmcnt(" #n ")" ::: "memory")

// ---------------- merged fp32 -> bf16 converts ----------------
__global__ __launch_bounds__(256) void cvt4(const float* __restrict__ s0,
                                            const float* __restrict__ s1,
                                            const float* __restrict__ s2,
                                            const float* __restrict__ s3,
                                            u16* __restrict__ d0, u16* __restrict__ d1,
                                            u16* __restrict__ d2, u16* __restrict__ d3,
                                            int n) {
    const int y = blockIdx.y;
    const float* src = (y == 0) ? s0 : (y == 1) ? s1 : (y == 2) ? s2 : s3;
    u16* dst = (y == 0) ? d0 : (y == 1) ? d1 : (y == 2) ? d2 : d3;
    int i = (blockIdx.x * 256 + threadIdx.x) * 4;
    if (i < n) {
        float4 f = *reinterpret_cast<const float4*>(src + i);
        u16x4 u = { f2bf(f.x), f2bf(f.y), f2bf(f.z), f2bf(f.w) };
        *reinterpret_cast<u16x4*>(dst + i) = u;
    }
}
__global__ __launch_bounds__(256) void cvt3(const float* __restrict__ s0,
                                            const float* __restrict__ s1,
                                            const float* __restrict__ s2,
                                            u16* __restrict__ d0, u16* __restrict__ d1,
                                            u16* __restrict__ d2, int n) {
    const int y = blockIdx.y;
    const float* src = (y == 0) ? s0 : (y == 1) ? s1 : s2;
    u16* dst = (y == 0) ? d0 : (y == 1) ? d1 : d2;
    int i = (blockIdx.x * 256 + threadIdx.x) * 4;
    if (i < n) {
        float4 f = *reinterpret_cast<const float4*>(src + i);
        u16x4 u = { f2bf(f.x), f2bf(f.y), f2bf(f.z), f2bf(f.w) };
        *reinterpret_cast<u16x4*>(dst + i) = u;
    }
}

// ---------------- merged QKV projection GEMM (z selects matrix) ----------------
// C[M,N] = A[M,K] * B[N,K]^T + bias. R6-proven fence/dbuf skeleton.
// z==0,1: bf16 [M][N] out. z==2: bf16 V^T head layout (b,h,dk,s).
// Grid (512,1,3) -> ~4 blocks/CU co-resident (vs 2 when serial): cross-block
// wave overlap fills the barrier stalls (m114 mechanism).
__global__ __launch_bounds__(256) void gemm_qkv(const u16* __restrict__ Aq,
                                                const u16* __restrict__ Ak,
                                                const u16* __restrict__ Av,
                                                const u16* __restrict__ Bq,
                                                const u16* __restrict__ Bk,
                                                const u16* __restrict__ Bv,
                                                const float* __restrict__ bq,
                                                const float* __restrict__ bk,
                                                const float* __restrict__ bv,
                                                u16* __restrict__ Cq,
                                                u16* __restrict__ Ck,
                                                u16* __restrict__ Cvp,
                                                int M, int N, int K) {
    __shared__ __align__(16) u16 As[2][128][32];
    __shared__ __align__(16) u16 Bs[2][128][32];
    const int z = blockIdx.z;
    const u16* A = (z == 0) ? Aq : (z == 1) ? Ak : Av;
    const u16* B = (z == 0) ? Bq : (z == 1) ? Bk : Bv;
    const float* bias = (z == 0) ? bq : (z == 1) ? bk : bv;
    u16* Cv = (z == 0) ? Cq : (z == 1) ? Ck : Cvp;
    const bool vmode = (z == 2);

    const int t = threadIdx.x, lane = t & 63, w = t >> 6;
    const int wr = w >> 1, wc = w & 1;
    const int l15 = lane & 15, l16 = lane >> 4;
    const int nwg = gridDim.x, ntiles = N >> 7;
    const int wg = blockIdx.x, chunk = nwg >> 3;
    const int swz = (wg & 7) * chunk + (wg >> 3);
    const int bm = (swz / ntiles) * 128, bn = (swz % ntiles) * 128;
    const int srow = w * 16 + (lane >> 2);
    const int sgr = (lane & 3) * 8;
    const u16* Ab = A + (size_t)bm * K;
    const u16* Bb = B + (size_t)bn * K;

    f32x4 acc[4][4];
#pragma unroll
    for (int i = 0; i < 4; i++)
#pragma unroll
        for (int j = 0; j < 4; j++) acc[i][j] = (f32x4){0.f, 0.f, 0.f, 0.f};

    auto stage = [&](int c, int k0) {
        gload16(Ab + (size_t)srow * K + k0 + sgr,        &As[c][w * 16][0]);
        gload16(Ab + (size_t)(64 + srow) * K + k0 + sgr, &As[c][64 + w * 16][0]);
        gload16(Bb + (size_t)srow * K + k0 + sgr,        &Bs[c][w * 16][0]);
        gload16(Bb + (size_t)(64 + srow) * K + k0 + sgr, &Bs[c][64 + w * 16][0]);
    };

    stage(0, 0);
    __syncthreads();

    const int NS = K >> 5;
    for (int i = 0; i < NS; ++i) {
        const int c = i & 1;
        WAIT_LGKM0();
        hard_barrier();
        if (i + 1 < NS) {
            stage(c ^ 1, (i + 1) * 32);
            WAIT_VMCNT(4);
        } else {
            WAIT_VMCNT(0);
        }
        hard_barrier();

        bf16x8 afr[4], bfr[4];
#pragma unroll
        for (int mi = 0; mi < 4; mi++)
            afr[mi] = *(const bf16x8*)&As[c][wr * 64 + mi * 16 + l15][l16 * 8];
#pragma unroll
        for (int ni = 0; ni < 4; ni++)
            bfr[ni] = *(const bf16x8*)&Bs[c][wc * 64 + ni * 16 + l15][l16 * 8];
#pragma unroll
        for (int mi = 0; mi < 4; mi++)
#pragma unroll
            for (int ni = 0; ni < 4; ni++)
                acc[mi][ni] = __builtin_amdgcn_mfma_f32_16x16x32_bf16(
                    afr[mi], bfr[ni], acc[mi][ni], 0, 0, 0);
    }

#pragma unroll
    for (int ni = 0; ni < 4; ni++) {
        const int col = bn + wc * 64 + ni * 16 + l15;
        const float bv2 = bias[col];
#pragma unroll
        for (int mi = 0; mi < 4; mi++) {
            const int r0 = bm + wr * 64 + mi * 16 + l16 * 4;
            if (vmode) {  // V^T head layout, 4 tokens packed along s
                const int bb = r0 >> 11, ss = r0 & 2047;
                const int hh = col >> 6, dk = col & 63;
                u16x4 pk;
#pragma unroll
                for (int r = 0; r < 4; r++) pk[r] = f2bf(acc[mi][ni][r] + bv2);
                *(u16x4*)&Cv[(((size_t)(bb * 16 + hh) * 64 + dk) << 11) + ss] = pk;
            } else {
#pragma unroll
                for (int r = 0; r < 4; r++)
                    Cv[(size_t)(r0 + r) * N + col] = f2bf(acc[mi][ni][r] + bv2);
            }
        }
    }
}

// ---------------- out-projection GEMM (f32 out) — R6-proven, unchanged ----------------
__global__ __launch_bounds__(256) void gemm_out(const u16* __restrict__ A,
                                                const u16* __restrict__ B,
                                                const float* __restrict__ bias,
                                                float* __restrict__ Cv,
                                                int M, int N, int K) {
    __shared__ __align__(16) u16 As[2][128][32];
    __shared__ __align__(16) u16 Bs[2][128][32];
    const int t = threadIdx.x, lane = t & 63, w = t >> 6;
    const int wr = w >> 1, wc = w & 1;
    const int l15 = lane & 15, l16 = lane >> 4;
    const int nwg = gridDim.x, ntiles = N >> 7;
    const int wg = blockIdx.x, chunk = nwg >> 3;
    const int swz = (wg & 7) * chunk + (wg >> 3);
    const int bm = (swz / ntiles) * 128, bn = (swz % ntiles) * 128;
    const int srow = w * 16 + (lane >> 2);
    const int sgr = (lane & 3) * 8;
    const u16* Ab = A + (size_t)bm * K;
    const u16* Bb = B + (size_t)bn * K;

    f32x4 acc[4][4];
#pragma unroll
    for (int i = 0; i < 4; i++)
#pragma unroll
        for (int j = 0; j < 4; j++) acc[i][j] = (f32x4){0.f, 0.f, 0.f, 0.f};

    auto stage = [&](int c, int k0) {
        gload16(Ab + (size_t)srow * K + k0 + sgr,        &As[c][w * 16][0]);
        gload16(Ab + (size_t)(64 + srow) * K + k0 + sgr, &As[c][64 + w * 16][0]);
        gload16(Bb + (size_t)srow * K + k0 + sgr,        &Bs[c][w * 16][0]);
        gload16(Bb + (size_t)(64 + srow) * K + k0 + sgr, &Bs[c][64 + w * 16][0]);
    };

    stage(0, 0);
    __syncthreads();

    const int NS = K >> 5;
    for (int i = 0; i < NS; ++i) {
        const int c = i & 1;
        WAIT_LGKM0();
        hard_barrier();
        if (i + 1 < NS) {
            stage(c ^ 1, (i + 1) * 32);
            WAIT_VMCNT(4);
        } else {
            WAIT_VMCNT(0);
        }
        hard_barrier();

        bf16x8 afr[4], bfr[4];
#pragma unroll
        for (int mi = 0; mi < 4; mi++)
            afr[mi] = *(const bf16x8*)&As[c][wr * 64 + mi * 16 + l15][l16 * 8];
#pragma unroll
        for (int ni = 0; ni < 4; ni++)
            bfr[ni] = *(const bf16x8*)&Bs[c][wc * 64 + ni * 16 + l15][l16 * 8];
#pragma unroll
        for (int mi = 0; mi < 4; mi++)
#pragma unroll
            for (int ni = 0; ni < 4; ni++)
                acc[mi][ni] = __builtin_amdgcn_mfma_f32_16x16x32_bf16(
                    afr[mi], bfr[ni], acc[mi][ni], 0, 0, 0);
    }

#pragma unroll
    for (int ni = 0; ni < 4; ni++) {
        const int col = bn + wc * 64 + ni * 16 + l15;
        const float bv = bias[col];
#pragma unroll
        for (int mi = 0; mi < 4; mi++) {
            const int r0 = bm + wr * 64 + mi * 16 + l16 * 4;
#pragma unroll
            for (int r = 0; r < 4; r++)
                Cv[(size_t)(r0 + r) * N + col] = acc[mi][ni][r] + bv;
        }
    }
}

// ---------------- flash attention: swapped-QK, packed P, MFMA row-sums, KVBLK=128 ----------------
// Block = 256 q of one (b,h); 4 waves x 64 q. KV tiles of 128 (two 64-key half-hoists),
// dbuf + R6 fences; barriers per block: 32 (vs 64 at KVBLK=64). vmcnt(8) counted wait.
__global__ __launch_bounds__(256, 2) void attn_fwd(const u16* __restrict__ Q,
                                                   const u16* __restrict__ Kg,
                                                   const u16* __restrict__ Vt,
                                                   const int* __restrict__ mask,
                                                   u16* __restrict__ O) {
    constexpr int S = 2048, D = 1024;
    __shared__ __align__(16) u16 Kl[2][2][2][64][32];  // [buf][kg][dk-half][key64][dk32]
    __shared__ __align__(16) u16 Vl[2][2][2][64][32];  // [buf][kg][k32-half][dk64][k32]
    __shared__ __align__(16) u16 Pl[4][16][68];
    __shared__ unsigned Mb[64];
    const int t = threadIdx.x, lane = t & 63, w = t >> 6;
    const int l15 = lane & 15, l16 = lane >> 4;
    const int wg = blockIdx.x;                         // 512 blocks, %8==0 -> bijective
    const int swz = (wg & 7) * 64 + (wg >> 3);
    const int q0 = (swz & 7) * 256, h = (swz >> 3) & 15, b = swz >> 7;
    const int qb = q0 + w * 64;
    const int srow = w * 16 + (lane >> 2);
    const int sgr = ((lane & 3) ^ ((lane >> 3) & 3)) * 8;   // pre-swizzled source granule
    const int gsw8 = (l16 ^ ((l15 >> 1) & 3)) * 8;          // swizzled read granule

    const u16* Khead = Kg + (size_t)b * S * D + h * 64;
    const u16* Vthead = Vt + (size_t)(b * 16 + h) * 64 * 2048;
    const int* mrow = mask + b * S;

    auto stage = [&](int c, int kt) {
#pragma unroll
        for (int kg = 0; kg < 2; kg++) {
            const int k0 = kt + kg * 64;
            gload16(Khead + (size_t)(k0 + srow) * D + sgr,        &Kl[c][kg][0][w * 16][0]);
            gload16(Khead + (size_t)(k0 + srow) * D + 32 + sgr,   &Kl[c][kg][1][w * 16][0]);
            gload16(Vthead + (size_t)srow * 2048 + k0 + sgr,      &Vl[c][kg][0][w * 16][0]);
            gload16(Vthead + (size_t)srow * 2048 + k0 + 32 + sgr, &Vl[c][kg][1][w * 16][0]);
        }
    };

    stage(0, 0);
    // pack mask bits (once)
#pragma unroll
    for (int j = 0; j < 8; j++) {
        unsigned long long bal = __ballot(mrow[j * 256 + w * 64 + lane] != 0);
        if (lane == 0) {
            Mb[(j * 4 + w) * 2]     = (unsigned)bal;
            Mb[(j * 4 + w) * 2 + 1] = (unsigned)(bal >> 32);
        }
    }

    // Q fragments (4 q-subtiles), pre-scaled by 0.125 * log2(e)
    constexpr float QSCALE = 0.125f * 1.44269504f;
    bf16x8 aq[4][2];
#pragma unroll
    for (int qt = 0; qt < 4; qt++)
#pragma unroll
        for (int ks = 0; ks < 2; ks++) {
            const size_t qi = ((size_t)b * S + qb + qt * 16 + l15) * D +
                              h * 64 + ks * 32 + l16 * 8;
            u16x8 raw = *(const u16x8*)&Q[qi];
            bf16x8 qv;
#pragma unroll
            for (int i = 0; i < 8; i++) qv[i] = (__bf16)(bf2f(raw[i]) * QSCALE);
            aq[qt][ks] = qv;
        }

    bf16x8 ones;
#pragma unroll
    for (int i = 0; i < 8; i++) ones[i] = (__bf16)1.0f;

    f32x4 acc[4][4];
    f32x4 accl[4];
#pragma unroll
    for (int qt = 0; qt < 4; qt++) {
        accl[qt] = (f32x4){0.f, 0.f, 0.f, 0.f};
#pragma unroll
        for (int dt = 0; dt < 4; dt++) acc[qt][dt] = (f32x4){0.f, 0.f, 0.f, 0.f};
    }

    __syncthreads();  // one-time full drain: buf0 staged + Mb visible

    for (int tile = 0; tile < S / 128; ++tile) {
        const int c = tile & 1;
        const int cur = tile * 128;
        WAIT_LGKM0();     // our LDS reads fully retired before anyone overwrites
        hard_barrier();   // barrier1
        if (tile + 1 < S / 128) {
            stage(c ^ 1, cur + 128);
            WAIT_VMCNT(8);   // 8 newest = next tile's loads -> current tile landed
        } else {
            WAIT_VMCNT(0);
        }
        hard_barrier();   // barrier2

#pragma unroll
        for (int kg = 0; kg < 2; kg++) {
            // hoist this 64-key half's K and V fragments (16 b128)
            bf16x8 kf0[4], kf1[4], vf0[4], vf1[4];
#pragma unroll
            for (int k4 = 0; k4 < 4; k4++) {
                kf0[k4] = *(const bf16x8*)&Kl[c][kg][0][k4 * 16 + l15][gsw8];
                kf1[k4] = *(const bf16x8*)&Kl[c][kg][1][k4 * 16 + l15][gsw8];
            }
#pragma unroll
            for (int dt = 0; dt < 4; dt++) {
                vf0[dt] = *(const bf16x8*)&Vl[c][kg][0][dt * 16 + l15][gsw8];
                vf1[dt] = *(const bf16x8*)&Vl[c][kg][1][dt * 16 + l15][gsw8];
            }

            // mask adds: key = cur + kg*64 + k4*16 + l16*4 + r
            const int mb0 = (cur >> 5) + kg * 2;
            const unsigned w0 = Mb[mb0], w1 = Mb[mb0 + 1];
            float madd[4][4];
#pragma unroll
            for (int k4 = 0; k4 < 4; k4++) {
                const unsigned wsel = (k4 < 2) ? w0 : w1;
                const unsigned bits = (wsel >> ((k4 & 1) * 16 + l16 * 4)) & 0xFu;
#pragma unroll
                for (int r = 0; r < 4; r++)
                    madd[k4][r] = ((bits >> r) & 1u) ? 0.f : -1.0e9f;
            }

#pragma unroll
            for (int qt = 0; qt < 4; qt++) {
#pragma unroll
                for (int k4 = 0; k4 < 4; k4++) {
                    f32x4 z = (f32x4){0.f, 0.f, 0.f, 0.f};
                    z = __builtin_amdgcn_mfma_f32_16x16x32_bf16(kf0[k4], aq[qt][0], z, 0, 0, 0);
                    z = __builtin_amdgcn_mfma_f32_16x16x32_bf16(kf1[k4], aq[qt][1], z, 0, 0, 0);
                    u16x4 pk;
#pragma unroll
                    for (int r = 0; r < 4; r++)
                        pk[r] = f2bf(__builtin_amdgcn_exp2f(z[r] + madd[k4][r]));
                    *(u16x4*)&Pl[w][l15][k4 * 16 + l16 * 4] = pk;  // packed b64
                }
                bf16x8 pa0 = *(const bf16x8*)&Pl[w][l15][l16 * 8];
                bf16x8 pa1 = *(const bf16x8*)&Pl[w][l15][32 + l16 * 8];
                accl[qt] = __builtin_amdgcn_mfma_f32_16x16x32_bf16(pa0, ones, accl[qt], 0, 0, 0);
                accl[qt] = __builtin_amdgcn_mfma_f32_16x16x32_bf16(pa1, ones, accl[qt], 0, 0, 0);
#pragma unroll
                for (int dt = 0; dt < 4; dt++) {
                    acc[qt][dt] = __builtin_amdgcn_mfma_f32_16x16x32_bf16(
                        pa0, vf0[dt], acc[qt][dt], 0, 0, 0);
                    acc[qt][dt] = __builtin_amdgcn_mfma_f32_16x16x32_bf16(
                        pa1, vf1[dt], acc[qt][dt], 0, 0, 0);
                }
            }
        }
    }

    // epilogue: accl[qt][r] = row sum for q = qt*16 + l16*4 + r
#pragma unroll
    for (int qt = 0; qt < 4; qt++) {
        f32x4 inv;
#pragma unroll
        for (int r = 0; r < 4; r++) inv[r] = 1.f / accl[qt][r];
#pragma unroll
        for (int dt = 0; dt < 4; dt++)
#pragma unroll
            for (int r = 0; r < 4; r++) {
                const int tok = qb + qt * 16 + l16 * 4 + r;
                O[((size_t)b * S + tok) * D + h * 64 + dt * 16 + l15] =
                    f2bf(acc[qt][dt][r] * inv[r]);
            }
    }
}

extern "C" void kernel_launch(void* const* d_in, const int* in_sizes, int n_in,
                              void* d_out, int out_size, void* d_ws, size_t ws_size,
                              hipStream_t stream) {
    const float* query = (const float*)d_in[0];
    const float* key   = (const float*)d_in[1];
    const float* value = (const float*)d_in[2];
    const int*   mask  = (const int*)d_in[3];
    const float* Wq = (const float*)d_in[4];
    const float* bq = (const float*)d_in[5];
    const float* Wk = (const float*)d_in[6];
    const float* bk = (const float*)d_in[7];
    const float* Wv = (const float*)d_in[8];
    const float* bv = (const float*)d_in[9];
    const float* Wo = (const float*)d_in[10];
    const float* bo = (const float*)d_in[11];
    float* out = (float*)d_out;

    constexpr int S = 2048, D = 1024;
    constexpr size_t MSZ = (size_t)4 * S * D;   // 8388608
    constexpr size_t WSZ = (size_t)D * D;       // 1048576
    const size_t need = 4 * WSZ * 2 + 4 * MSZ * 2;  // 72 MB
    if (ws_size < need) return;

    char* p = (char*)d_ws;
    u16* Wqb = (u16*)p; p += WSZ * 2;
    u16* Wkb = (u16*)p; p += WSZ * 2;
    u16* Wvb = (u16*)p; p += WSZ * 2;
    u16* Wob = (u16*)p; p += WSZ * 2;
    u16* Aq  = (u16*)p; p += MSZ * 2;  // bf16 query activation; later reused as Xb
    u16* Qb  = (u16*)p; p += MSZ * 2;
    u16* Kb  = (u16*)p; p += MSZ * 2;
    u16* Vtb = (u16*)p; p += MSZ * 2;  // (b,h,dk,s)
    // Ak/Av live in d_out (32 MB scratch, dead until final GEMM rewrites it fully)
    u16* Ak = (u16*)d_out;
    u16* Av = (u16*)d_out + MSZ;
    u16* Xb = Aq;  // attn output aliases Aq (dead after projections)

    cvt4<<<dim3(WSZ / 1024, 4), 256, 0, stream>>>(Wq, Wk, Wv, Wo,
                                                  Wqb, Wkb, Wvb, Wob, (int)WSZ);
    cvt3<<<dim3(MSZ / 1024, 3), 256, 0, stream>>>(query, key, value,
                                                  Aq, Ak, Av, (int)MSZ);
    gemm_qkv<<<dim3(512, 1, 3), 256, 0, stream>>>(Aq, Ak, Av, Wqb, Wkb, Wvb,
                                                  bq, bk, bv, Qb, Kb, Vtb,
                                                  8192, 1024, 1024);
    attn_fwd<<<512, 256, 0, stream>>>(Qb, Kb, Vtb, mask, Xb);
    gemm_out<<<512, 256, 0, stream>>>(Xb, Wob, bo, out, 8192, 1024, 1024);
}